// Round 1
// baseline (419.897 us; speedup 1.0000x reference)
//
#include <hip/hip_runtime.h>
#include <stdint.h>

// VectorQuantizer: z [65536,64] f32, codebook [1024,64] f32
// out = concat(q [B,C], z_q_st [B,D], loss [1]) all f32
#define NB    65536
#define NC    1024
#define ND    64
#define BR    32            // rows per block
#define NW    4             // waves per block (256 threads)

// ws layout (floats):
//  [0]              loss accumulator
//  [64 .. 1088)     wn2 (1024)
//  [2048 .. 67584)  cbT (64*1024), cbT[k*1024 + c] = cb[c*64 + k]

__global__ void vq_prep(const float* __restrict__ cb, float* __restrict__ ws) {
    int c = blockIdx.x * 64 + threadIdx.x;       // 0..1023
    float s = 0.f;
    #pragma unroll 8
    for (int k = 0; k < ND; ++k) {
        float v = cb[c * ND + k];
        ws[2048 + k * NC + c] = v;               // transpose (coalesced store)
        s = fmaf(v, v, s);
    }
    ws[64 + c] = s;                              // wn2
}

__device__ inline unsigned long long shfl_xor_u64(unsigned long long v, int m) {
    unsigned lo = (unsigned)v, hi = (unsigned)(v >> 32);
    lo = __shfl_xor(lo, m, 64);
    hi = __shfl_xor(hi, m, 64);
    return ((unsigned long long)hi << 32) | (unsigned long long)lo;
}

__global__ __launch_bounds__(256, 2) void vq_main(
    const float* __restrict__ z, const float* __restrict__ cb,
    const float* __restrict__ ws, float* __restrict__ q_out,
    float* __restrict__ zq_out, float* __restrict__ loss_acc)
{
    const int rb = blockIdx.x * BR;              // block's first row (uniform)
    const int L  = threadIdx.x;                  // c-quad id, 0..255
    const float* __restrict__ zb = z + (size_t)rb * ND;      // uniform base -> s_load
    const float4* __restrict__ cbT4 = (const float4*)(ws + 2048);
    const float4* __restrict__ wn24 = (const float4*)(ws + 64);

    __shared__ float part[256];
    __shared__ float zn2s[BR];
    __shared__ float sred[NW * BR];
    __shared__ unsigned long long kred[NW * BR];

    // ---- zn2 per row (order vs numpy irrelevant: uniform shift per row) ----
    {
        const float4* z4 = (const float4*)zb;
        float4 a = z4[L * 2 + 0];
        float4 b = z4[L * 2 + 1];
        part[L] = a.x*a.x + a.y*a.y + a.z*a.z + a.w*a.w
                + b.x*b.x + b.y*b.y + b.z*b.z + b.w*b.w;
    }
    __syncthreads();
    if (L < BR) {
        float s = 0.f;
        #pragma unroll
        for (int j = 0; j < 8; ++j) s += part[L * 8 + j];
        zn2s[L] = s;
    }
    __syncthreads();

    // ---- main K-loop: acc[r] = dot(z[rb+r,:], cb[c,:]) for c = 4L..4L+3 ----
    float4 acc[BR];
    #pragma unroll
    for (int r = 0; r < BR; ++r) acc[r] = make_float4(0.f, 0.f, 0.f, 0.f);

    for (int kk = 0; kk < ND; kk += 4) {
        float4 c0 = cbT4[(size_t)(kk + 0) * 256 + L];
        float4 c1 = cbT4[(size_t)(kk + 1) * 256 + L];
        float4 c2 = cbT4[(size_t)(kk + 2) * 256 + L];
        float4 c3 = cbT4[(size_t)(kk + 3) * 256 + L];
        #pragma unroll
        for (int r = 0; r < BR; ++r) {
            // uniform (blockIdx-only) addresses -> scalar loads into SGPRs
            float z0 = zb[r * ND + kk + 0];
            float z1 = zb[r * ND + kk + 1];
            float z2 = zb[r * ND + kk + 2];
            float z3 = zb[r * ND + kk + 3];
            float4 a = acc[r];
            a.x = fmaf(z0, c0.x, a.x); a.y = fmaf(z0, c0.y, a.y);
            a.z = fmaf(z0, c0.z, a.z); a.w = fmaf(z0, c0.w, a.w);
            a.x = fmaf(z1, c1.x, a.x); a.y = fmaf(z1, c1.y, a.y);
            a.z = fmaf(z1, c1.z, a.z); a.w = fmaf(z1, c1.w, a.w);
            a.x = fmaf(z2, c2.x, a.x); a.y = fmaf(z2, c2.y, a.y);
            a.z = fmaf(z2, c2.z, a.z); a.w = fmaf(z2, c2.w, a.w);
            a.x = fmaf(z3, c3.x, a.x); a.y = fmaf(z3, c3.y, a.y);
            a.z = fmaf(z3, c3.z, a.z); a.w = fmaf(z3, c3.w, a.w);
            acc[r] = a;
        }
    }

    // ---- epilogue stage 1: d -> q_unnorm, per-row wave reductions ----
    const int wv = L >> 6, lane = L & 63;
    float4 w4 = wn24[L];
    const int c0i = 4 * L;

    #pragma unroll
    for (int r = 0; r < BR; ++r) {
        float zn2r = zn2s[r];
        float4 a = acc[r];
        // exact reference association: (zn2 + wn2) - 2*dot
        float d0 = (zn2r + w4.x) - 2.f * a.x;
        float d1 = (zn2r + w4.y) - 2.f * a.y;
        float d2 = (zn2r + w4.z) - 2.f * a.z;
        float d3 = (zn2r + w4.w) - 2.f * a.w;
        float q0 = __builtin_amdgcn_rcpf(1.f + d0);
        float q1 = __builtin_amdgcn_rcpf(1.f + d1);
        float q2 = __builtin_amdgcn_rcpf(1.f + d2);
        float q3 = __builtin_amdgcn_rcpf(1.f + d3);
        acc[r] = make_float4(q0, q1, q2, q3);
        float ps = ((q0 + q1) + q2) + q3;
        // argmax with numpy tie-break (lowest c wins): d>=0 so bits are monotone
        unsigned long long k0 = ((unsigned long long)__float_as_uint(d0) << 32) | (unsigned)(1023 - (c0i + 0));
        unsigned long long k1 = ((unsigned long long)__float_as_uint(d1) << 32) | (unsigned)(1023 - (c0i + 1));
        unsigned long long k2 = ((unsigned long long)__float_as_uint(d2) << 32) | (unsigned)(1023 - (c0i + 2));
        unsigned long long k3 = ((unsigned long long)__float_as_uint(d3) << 32) | (unsigned)(1023 - (c0i + 3));
        unsigned long long ka = k0 > k1 ? k0 : k1;
        unsigned long long kb = k2 > k3 ? k2 : k3;
        unsigned long long key = ka > kb ? ka : kb;
        #pragma unroll
        for (int m = 1; m < 64; m <<= 1) {
            ps += __shfl_xor(ps, m, 64);
            unsigned long long ok = shfl_xor_u64(key, m);
            key = key > ok ? key : ok;
        }
        if (lane == 0) { sred[wv * BR + r] = ps; kred[wv * BR + r] = key; }
    }
    __syncthreads();

    // ---- stage 2: combine waves, normalize, store q ----
    #pragma unroll
    for (int r = 0; r < BR; ++r) {
        float fs = ((sred[0 * BR + r] + sred[1 * BR + r]) + sred[2 * BR + r]) + sred[3 * BR + r];
        float inv = __builtin_amdgcn_rcpf(fs);
        float4 a = acc[r];
        float4 o = make_float4(a.x * inv, a.y * inv, a.z * inv, a.w * inv);
        ((float4*)q_out)[(size_t)(rb + r) * (NC / 4) + L] = o;
    }

    // ---- z_q_st + loss ----
    float lsum = 0.f;
    #pragma unroll
    for (int i = 0; i < BR / NW; ++i) {
        int r = wv * (BR / NW) + i;
        unsigned long long ka = kred[0 * BR + r] > kred[1 * BR + r] ? kred[0 * BR + r] : kred[1 * BR + r];
        unsigned long long kb = kred[2 * BR + r] > kred[3 * BR + r] ? kred[2 * BR + r] : kred[3 * BR + r];
        unsigned long long km = ka > kb ? ka : kb;
        int bc = 1023 - (int)(unsigned)(km & 0xffffffffULL);
        float cv = cb[(size_t)bc * ND + lane];
        float zv = z[(size_t)(rb + r) * ND + lane];
        float t = cv - zv;                       // z_q - z
        zq_out[(size_t)(rb + r) * ND + lane] = zv + t;   // z + sg(z_q - z)
        lsum = fmaf(t, t, lsum);
    }
    #pragma unroll
    for (int m = 1; m < 64; m <<= 1) lsum += __shfl_xor(lsum, m, 64);
    if (lane == 0) atomicAdd(loss_acc, lsum);
}

__global__ void vq_fin(const float* __restrict__ ws, float* __restrict__ loss_out) {
    if (threadIdx.x == 0) {
        float m = ws[0] / (float)((size_t)NB * ND);
        loss_out[0] = 0.25f * m + m;             // BETA*mean + mean
    }
}

extern "C" void kernel_launch(void* const* d_in, const int* in_sizes, int n_in,
                              void* d_out, int out_size, void* d_ws, size_t ws_size,
                              hipStream_t stream) {
    const float* z  = (const float*)d_in[0];
    const float* cb = (const float*)d_in[1];
    float* q_out    = (float*)d_out;
    float* zq_out   = q_out + (size_t)NB * NC;
    float* loss_out = zq_out + (size_t)NB * ND;
    float* ws       = (float*)d_ws;

    hipMemsetAsync(d_ws, 0, 4, stream);                      // zero loss accumulator
    vq_prep<<<NC / 64, 64, 0, stream>>>(cb, ws);
    vq_main<<<NB / BR, 256, 0, stream>>>(z, cb, ws, q_out, zq_out, ws);
    vq_fin<<<1, 64, 0, stream>>>(ws, loss_out);
}